// Round 11
// baseline (100.246 us; speedup 1.0000x reference)
//
#include <hip/hip_runtime.h>

typedef _Float16 h8 __attribute__((ext_vector_type(8)));
typedef _Float16 h4 __attribute__((ext_vector_type(4)));
typedef _Float16 h2 __attribute__((ext_vector_type(2)));
typedef float f4 __attribute__((ext_vector_type(4)));

#define NT 7        // n-tiles: 112 output features (100 real)
#define KC 4        // k-chunks of 32: k=0..99 real, k=100 -> t, k=101 -> 1
#define HSTRIDE 104 // halves per comb row (208 B, 16B-aligned)

// TWO WAVES PER TREE (subtree split), ring-compacted in-place comb panels,
// barrier-free heavy phase (see R10 comments). THIS ROUND: kc-outer/nt-inner
// MFMA order with 7 parallel accumulators — consecutive MFMAs belong to
// different dependency chains (re-use distance 7 issues > dep latency), so
// the matrix pipe streams at throughput instead of stalling ~35 cy per
// dependent MFMA. Epilogue deferred to its own 7-independent-chain phase.
__global__ __launch_bounds__(128, 1)
void grnn_fused(const float* __restrict__ times,
                const float* __restrict__ Qw,
                const float* __restrict__ Qb,
                const float* __restrict__ Ww,
                const float* __restrict__ Wb,
                const float* __restrict__ Pw,
                const float* __restrict__ Pb,
                float* __restrict__ out)
{
  __shared__ __align__(16) _Float16 Cs[128][HSTRIDE]; // 26624 B
  __shared__ __align__(16) _Float16 trash[512];       // sink for dead lanes
  __shared__ __align__(4)  _Float16 ts_fold[512];     // heap t[0..510] as f16
  __shared__ __align__(4)  h2 tsp[256];               // leaf pair (t[511+2n], t[512+2n])

  const int tid  = threadIdx.x;        // 0..127
  const int wave = tid >> 6;           // 0,1
  const int lane = tid & 63;
  const int l15  = lane & 15;
  const int kg   = lane >> 4;
  const int tree = blockIdx.x;
  const int PB   = wave << 6;          // panel base row

  // ---- persistent W fragments (B[k][n]=Ww[n][k]); fold k=100 -> Qw,
  //      k=101 -> Qb+Wb ----
  h8 wf[NT][KC];
  #pragma unroll
  for (int nt = 0; nt < NT; ++nt) {
    const int r = nt * 16 + l15;
    #pragma unroll
    for (int kc = 0; kc < KC; ++kc) {
      h8 v;
      #pragma unroll
      for (int j = 0; j < 8; ++j) v[j] = (_Float16)0.f;
      if (r < 100) {
        const int kb = kc * 32 + kg * 8;
        if (kc < 3) {
          const f4 w0 = *(const f4*)&Ww[r * 100 + kb];
          const f4 w1 = *(const f4*)&Ww[r * 100 + kb + 4];
          #pragma unroll
          for (int j = 0; j < 4; ++j) {
            v[j]     = (_Float16)w0[j];
            v[j + 4] = (_Float16)w1[j];
          }
        } else if (kg == 0) {
          const f4 w0 = *(const f4*)&Ww[r * 100 + 96];
          #pragma unroll
          for (int j = 0; j < 4; ++j) v[j] = (_Float16)w0[j];
          v[4] = (_Float16)Qw[r];            // k=100
          v[5] = (_Float16)(Qb[r] + Wb[r]);  // k=101
        }
      }
      wf[nt][kc] = v;
    }
  }

  // ---- cooperative staging (128 threads), then the one barrier ----
  {
    const float* tg = times + tree * 1023;
    #pragma unroll
    for (int q = 0; q < 4; ++q) {
      const int ix = tid + 128 * q;
      if (ix < 511) ts_fold[ix] = (_Float16)tg[ix];
    }
    #pragma unroll
    for (int q = 0; q < 2; ++q) {
      const int pr = tid + 128 * q;    // 0..255
      tsp[pr] = (h2){(_Float16)tg[511 + 2 * pr], (_Float16)tg[512 + 2 * pr]};
    }
  }
  __syncthreads();

// MFMA tile, kc-outer/nt-inner (7 parallel acc chains), then a deferred
// epilogue: cvt->relu->DPP quad_perm(1,0,3,2) sibling add -> even-l15 lanes
// store comb row RW; dead lanes (odd l15, nt6 kg!=0) store to trash.
#define DO_MT(AFR, RW) do {                                                   \
    f4 acc_[NT];                                                              \
    _Pragma("unroll")                                                         \
    for (int nt_ = 0; nt_ < NT; ++nt_)                                        \
      acc_[nt_] = (f4){0.f, 0.f, 0.f, 0.f};                                   \
    _Pragma("unroll")                                                         \
    for (int kc_ = 0; kc_ < KC; ++kc_) {                                      \
      _Pragma("unroll")                                                       \
      for (int nt_ = 0; nt_ < NT; ++nt_)                                      \
        acc_[nt_] = __builtin_amdgcn_mfma_f32_16x16x32_f16(wf[nt_][kc_],      \
                                              AFR[kc_], acc_[nt_], 0, 0, 0);  \
    }                                                                         \
    const int rw_ = (RW);                                                     \
    _Float16* pv_ = (l15 & 1) ? &trash[lane * 4] : &Cs[rw_][kg * 4];          \
    _Float16* p6_ = kg ? &trash[lane * 4] : pv_;                              \
    const h2 z2_ = {(_Float16)0.f, (_Float16)0.f};                            \
    _Pragma("unroll")                                                         \
    for (int nt_ = 0; nt_ < NT; ++nt_) {                                      \
      h2 c0_ = {(_Float16)acc_[nt_][0], (_Float16)acc_[nt_][1]};              \
      h2 c1_ = {(_Float16)acc_[nt_][2], (_Float16)acc_[nt_][3]};              \
      c0_ = __builtin_elementwise_max(c0_, z2_);                              \
      c1_ = __builtin_elementwise_max(c1_, z2_);                              \
      int d0_ = __builtin_amdgcn_mov_dpp(__builtin_bit_cast(int, c0_),        \
                                         0xB1, 0xF, 0xF, true);               \
      int d1_ = __builtin_amdgcn_mov_dpp(__builtin_bit_cast(int, c1_),        \
                                         0xB1, 0xF, 0xF, true);               \
      c0_ = c0_ + __builtin_bit_cast(h2, d0_);                                \
      c1_ = c1_ + __builtin_bit_cast(h2, d1_);                                \
      h4 hv_ = {c0_[0], c0_[1], c1_[0], c1_[1]};                              \
      *(h4*)((nt_ == 6 ? p6_ : pv_) + nt_ * 16) = hv_;                        \
    }                                                                         \
  } while (0)

// Root: no sibling add; only l15==0 stores, into row 0.
#define DO_MT_ROOT(AFR) do {                                                  \
    f4 acc_[NT];                                                              \
    _Pragma("unroll")                                                         \
    for (int nt_ = 0; nt_ < NT; ++nt_)                                        \
      acc_[nt_] = (f4){0.f, 0.f, 0.f, 0.f};                                   \
    _Pragma("unroll")                                                         \
    for (int kc_ = 0; kc_ < KC; ++kc_) {                                      \
      _Pragma("unroll")                                                       \
      for (int nt_ = 0; nt_ < NT; ++nt_)                                      \
        acc_[nt_] = __builtin_amdgcn_mfma_f32_16x16x32_f16(wf[nt_][kc_],      \
                                              AFR[kc_], acc_[nt_], 0, 0, 0);  \
    }                                                                         \
    _Float16* pv_ = (l15 == 0) ? &Cs[0][kg * 4] : &trash[lane * 4];           \
    _Float16* p6_ = kg ? &trash[lane * 4] : pv_;                              \
    const h2 z2_ = {(_Float16)0.f, (_Float16)0.f};                            \
    _Pragma("unroll")                                                         \
    for (int nt_ = 0; nt_ < NT; ++nt_) {                                      \
      h2 c0_ = {(_Float16)acc_[nt_][0], (_Float16)acc_[nt_][1]};              \
      h2 c1_ = {(_Float16)acc_[nt_][2], (_Float16)acc_[nt_][3]};              \
      c0_ = __builtin_elementwise_max(c0_, z2_);                              \
      c1_ = __builtin_elementwise_max(c1_, z2_);                              \
      h4 hv_ = {c0_[0], c0_[1], c1_[0], c1_[1]};                              \
      *(h4*)((nt_ == 6 ? p6_ : pv_) + nt_ * 16) = hv_;                        \
    }                                                                         \
  } while (0)

// af for one tile: comb row ROW, fold slot from ts_fold[TSI] (kg!=0 lanes'
// af[3] garbage is harmless — multiplies wf==0).
#define LOAD_AFR(AFR, ROW, TSI) do {                                          \
    const int row_ = (ROW);                                                   \
    AFR[0] = *(const h8*)&Cs[row_][kg * 8];                                   \
    AFR[1] = *(const h8*)&Cs[row_][32 + kg * 8];                              \
    AFR[2] = *(const h8*)&Cs[row_][64 + kg * 8];                              \
    h4 lo_ = *(const h4*)&Cs[row_][96];                                       \
    h4 hi_ = {ts_fold[TSI], (_Float16)1.f, (_Float16)0.f, (_Float16)0.f};     \
    AFR[3] = __builtin_shufflevector(lo_, hi_, 0, 1, 2, 3, 4, 5, 6, 7);       \
  } while (0)

  // ---- level 8: 8 tiles/wave; leaf comb in packed f16 VALU. qwp/qbp scoped
  //      here so their 64 VGPRs die before the heavy pipeline. ----
  {
    h8 qwp[KC], qbp[KC];
    #pragma unroll
    for (int kc = 0; kc < KC; ++kc) {
      const int kb = kc * 32 + kg * 8;
      #pragma unroll
      for (int j = 0; j < 8; ++j) {
        const int ix = kb + j;
        qwp[kc][j] = (ix < 100) ? (_Float16)Qw[ix] : (_Float16)0.f;
        qbp[kc][j] = (ix < 100) ? (_Float16)Qb[ix] : (_Float16)0.f;
      }
    }
    const h8 z8 = {(_Float16)0.f, (_Float16)0.f, (_Float16)0.f, (_Float16)0.f,
                   (_Float16)0.f, (_Float16)0.f, (_Float16)0.f, (_Float16)0.f};
    #pragma unroll 2
    for (int i = 0; i < 8; ++i) {
      const h2 tp = tsp[128 * wave + 16 * i + l15];
      const _Float16 t0 = tp[0], t1 = tp[1];
      h8 afl[KC];
      #pragma unroll
      for (int kc = 0; kc < KC; ++kc) {
        h8 a = qwp[kc] * t0 + qbp[kc];
        h8 b = qwp[kc] * t1 + qbp[kc];
        a = __builtin_elementwise_max(a, z8);
        b = __builtin_elementwise_max(b, z8);
        afl[kc] = a + b;
      }
      afl[3][4] = ts_fold[255 + 128 * wave + 16 * i + l15];
      afl[3][5] = (_Float16)1.f;
      DO_MT(afl, PB + 8 * i + (l15 >> 1));
    }
  }

  // ---- levels 7,6,5 per wave: ring-compacted prefetch pipeline ----
  {
    h8 af[KC], afn[KC];
    LOAD_AFR(af, PB + l15, 127 + 64 * wave + l15);                    // (7,0)
    LOAD_AFR(afn, PB + 16 + l15, 127 + 64 * wave + 16 + l15);         // (7,1)
    DO_MT(af, PB + (l15 >> 1));
    #pragma unroll
    for (int c = 0; c < KC; ++c) af[c] = afn[c];
    LOAD_AFR(afn, PB + 32 + l15, 127 + 64 * wave + 32 + l15);         // (7,2)
    DO_MT(af, PB + 16 + (l15 >> 1));
    #pragma unroll
    for (int c = 0; c < KC; ++c) af[c] = afn[c];
    LOAD_AFR(afn, PB + 48 + l15, 127 + 64 * wave + 48 + l15);         // (7,3)
    DO_MT(af, PB + 32 + (l15 >> 1));
    #pragma unroll
    for (int c = 0; c < KC; ++c) af[c] = afn[c];
    // (6,0): reads PB+{0..7,16..23} — written by (7,0),(7,1).
    LOAD_AFR(afn, PB + 16 * (l15 >> 3) + (l15 & 7), 63 + 32 * wave + l15);
    DO_MT(af, PB + 48 + (l15 >> 1));                                  // (7,3)
    #pragma unroll
    for (int c = 0; c < KC; ++c) af[c] = afn[c];
    // (6,1): reads PB+{32..39,48..55} — (7,3) stores precede in program order.
    LOAD_AFR(afn, PB + 32 + 16 * (l15 >> 3) + (l15 & 7),
             63 + 32 * wave + 16 + l15);
    DO_MT(af, PB + (l15 >> 1));                                       // (6,0)
    #pragma unroll
    for (int c = 0; c < KC; ++c) af[c] = afn[c];
    DO_MT(af, PB + 32 + (l15 >> 1));                                  // (6,1)
    // (5,0): needs (6,1)'s rows 32..39 -> late load.
    LOAD_AFR(af, PB + 32 * (l15 >> 3) + (l15 & 7), 31 + 16 * wave + l15);
    DO_MT(af, PB + (l15 >> 1));                                       // (5,0)
  }
  __syncthreads();

  // ---- tail: wave0 only. L4 reads both panels (rows 0..7 / 64..71). ----
  if (wave == 0) {
    h8 af[KC];
    LOAD_AFR(af, (l15 < 8) ? l15 : (56 + l15), 15 + l15);             // L4
    DO_MT(af, (l15 >> 1));
    #pragma unroll 1
    for (int d = 3; d >= 1; --d) {                                    // L3..L1
      LOAD_AFR(af, l15, (1 << d) - 1 + l15);
      DO_MT(af, (l15 >> 1));
    }
    LOAD_AFR(af, l15, l15);                                           // root
    DO_MT_ROOT(af);

    // ---- projection: out[p] = root . Pw[p] + Pb[p], p<5 ----
    #pragma unroll 1
    for (int p = 0; p < 5; ++p) {
      float v = (float)Cs[0][lane] * Pw[p * 100 + lane];
      if (lane < 36) v += (float)Cs[0][64 + lane] * Pw[p * 100 + 64 + lane];
      v += __shfl_xor(v, 32, 64);
      v += __shfl_xor(v, 16, 64);
      v += __shfl_xor(v, 8, 64);
      v += __shfl_xor(v, 4, 64);
      v += __shfl_xor(v, 2, 64);
      v += __shfl_xor(v, 1, 64);
      if (lane == 0) out[tree * 5 + p] = v + Pb[p];
    }
  }
#undef DO_MT
#undef DO_MT_ROOT
#undef LOAD_AFR
}

extern "C" void kernel_launch(void* const* d_in, const int* in_sizes, int n_in,
                              void* d_out, int out_size, void* d_ws, size_t ws_size,
                              hipStream_t stream) {
  (void)n_in; (void)out_size; (void)d_ws; (void)ws_size;
  const float* times = (const float*)d_in[0];
  const float* Qw = (const float*)d_in[1];
  const float* Qb = (const float*)d_in[2];
  const float* Ww = (const float*)d_in[3];
  const float* Wb = (const float*)d_in[4];
  const float* Pw = (const float*)d_in[5];
  const float* Pb = (const float*)d_in[6];
  float* outp = (float*)d_out;
  const int B = in_sizes[0] / 1023;   // 1024 trees, 2 waves each
  grnn_fused<<<dim3(B), dim3(128), 0, stream>>>(times, Qw, Qb, Ww, Wb, Pw, Pb, outp);
}

// Round 13
// 98.173 us; speedup vs baseline: 1.0211x; 1.0211x over previous
//
#include <hip/hip_runtime.h>

typedef _Float16 h8 __attribute__((ext_vector_type(8)));
typedef _Float16 h4 __attribute__((ext_vector_type(4)));
typedef _Float16 h2 __attribute__((ext_vector_type(2)));
typedef float f4 __attribute__((ext_vector_type(4)));
typedef float f16v __attribute__((ext_vector_type(16)));

#define HSTRIDE 104 // halves per comb row (208 B, 16B-aligned)

// ONE WAVE = ONE TREE, 32x32x16 MFMA: one tile = 32 nodes x 32 features.
// Per tree: 20 tiles / 560 MFMA issues (vs 36 / 1008 with 16x16x32) — halves
// per-wave instruction count, LDS ops, and epilogue work. In-place comb
// buffer: level tile i reads rows 32i..32i+31, writes 16i..16i+15 (same-wave
// DS is in-order -> read-before-write safe; later tiles read higher rows).
// A operand (W): A[f=lane&31][k=8*(lane>>5)+j]; B (comb): B[k][n=lane&31],
// same k map. D: col n=lane&31, row f=(reg&3)+8*(reg>>2)+4*(lane>>5).
__global__ __launch_bounds__(64, 1)
void grnn_fused(const float* __restrict__ times,
                const float* __restrict__ Qw,
                const float* __restrict__ Qb,
                const float* __restrict__ Ww,
                const float* __restrict__ Wb,
                const float* __restrict__ Pw,
                const float* __restrict__ Pb,
                float* __restrict__ out)
{
  __shared__ __align__(16) _Float16 Cs[128][HSTRIDE]; // 26624 B comb buffer
  __shared__ __align__(16) _Float16 trash[512];       // dead-lane store sink
  __shared__ __align__(4)  _Float16 ts_fold[512];     // heap t[0..510] as f16
  __shared__ __align__(4)  h2 tsp[256];               // leaf pair (t[511+2n], t[512+2n])
  __shared__ __align__(16) _Float16 qwh[112];         // Qw as f16 (0-padded)
  __shared__ __align__(16) _Float16 qbh[112];         // Qb as f16 (0-padded)

  const int lane = threadIdx.x;        // 0..63
  const int c    = lane & 31;          // node/feature column
  const int hw   = lane >> 5;          // k half: k = 16kc + 8hw + j
  const int tree = blockIdx.x;

  // ---- stage times + q tables (single wave: no barriers ever) ----
  {
    const float* tg = times + tree * 1023;
    #pragma unroll
    for (int q = 0; q < 8; ++q) {
      const int ix = lane + 64 * q;
      if (ix < 511) ts_fold[ix] = (_Float16)tg[ix];
    }
    #pragma unroll
    for (int q = 0; q < 4; ++q) {
      const int pr = lane + 64 * q;
      tsp[pr] = (h2){(_Float16)tg[511 + 2 * pr], (_Float16)tg[512 + 2 * pr]};
    }
    #pragma unroll
    for (int q = 0; q < 2; ++q) {
      const int ix = lane + 64 * q;
      if (ix < 112) {
        qwh[ix] = (ix < 100) ? (_Float16)Qw[ix] : (_Float16)0.f;
        qbh[ix] = (ix < 100) ? (_Float16)Qb[ix] : (_Float16)0.f;
      }
    }
  }

  // ---- persistent W fragments as MFMA A operand: wf[ft][kc] holds
  //      A[f=32ft+c][k=16kc+8hw+j]; fold k=100 -> Qw[f], k=101 -> Qb+Wb ----
  h8 wf[4][7];
  #pragma unroll
  for (int ft = 0; ft < 4; ++ft) {
    const int r = 32 * ft + c;
    #pragma unroll
    for (int kc = 0; kc < 7; ++kc) {
      h8 v;
      #pragma unroll
      for (int j = 0; j < 8; ++j) v[j] = (_Float16)0.f;
      if (r < 100) {
        if (kc < 6) {
          const int kb = 16 * kc + 8 * hw;
          const f4 w0 = *(const f4*)&Ww[r * 100 + kb];
          const f4 w1 = *(const f4*)&Ww[r * 100 + kb + 4];
          #pragma unroll
          for (int j = 0; j < 4; ++j) {
            v[j]     = (_Float16)w0[j];
            v[j + 4] = (_Float16)w1[j];
          }
        } else if (hw == 0) {            // k = 96..103
          const f4 w0 = *(const f4*)&Ww[r * 100 + 96];
          #pragma unroll
          for (int j = 0; j < 4; ++j) v[j] = (_Float16)w0[j];
          v[4] = (_Float16)Qw[r];        // k=100
          v[5] = (_Float16)(Qb[r] + Wb[r]); // k=101
        }
      }
      wf[ft][kc] = v;
    }
  }

// MFMA burst: 4 independent acc chains (ft), 7 kc each. Epilogue: relu ->
// pack f16 -> (non-root) DPP quad_perm(1,0,3,2) sibling add (lane^1 = node
// n^1) -> store h4 groups at col 32ft+8g+4hw. BSE = comb-row base for live
// lanes (even c < NN), trash for dead; ft3 real only for hw==0, g==0
// (features 96..99).
#define DO_TILE(BF, BSE, DODPP) do {                                          \
    f16v acc_[4];                                                             \
    _Pragma("unroll")                                                         \
    for (int ft_ = 0; ft_ < 4; ++ft_)                                         \
      _Pragma("unroll")                                                       \
      for (int e_ = 0; e_ < 16; ++e_) acc_[ft_][e_] = 0.f;                    \
    _Pragma("unroll")                                                         \
    for (int kc_ = 0; kc_ < 7; ++kc_) {                                       \
      _Pragma("unroll")                                                       \
      for (int ft_ = 0; ft_ < 4; ++ft_)                                       \
        acc_[ft_] = __builtin_amdgcn_mfma_f32_32x32x16_f16(wf[ft_][kc_],      \
                                              BF[kc_], acc_[ft_], 0, 0, 0);   \
    }                                                                         \
    _Float16* b3_ = (hw == 0) ? (BSE) : &trash[lane * 4];                     \
    _Pragma("unroll")                                                         \
    for (int ft_ = 0; ft_ < 4; ++ft_) {                                       \
      _Pragma("unroll")                                                       \
      for (int g_ = 0; g_ < 4; ++g_) {                                        \
        if (ft_ < 3 || (g_ == 0)) {                                           \
          float a0_ = fmaxf(acc_[ft_][4 * g_ + 0], 0.f);                      \
          float a1_ = fmaxf(acc_[ft_][4 * g_ + 1], 0.f);                      \
          float a2_ = fmaxf(acc_[ft_][4 * g_ + 2], 0.f);                      \
          float a3_ = fmaxf(acc_[ft_][4 * g_ + 3], 0.f);                      \
          h2 lo_ = __builtin_bit_cast(h2,                                     \
                       __builtin_amdgcn_cvt_pkrtz(a0_, a1_));                 \
          h2 hi_ = __builtin_bit_cast(h2,                                     \
                       __builtin_amdgcn_cvt_pkrtz(a2_, a3_));                 \
          if (DODPP) {                                                        \
            int d0_ = __builtin_amdgcn_mov_dpp(__builtin_bit_cast(int, lo_),  \
                                               0xB1, 0xF, 0xF, true);         \
            int d1_ = __builtin_amdgcn_mov_dpp(__builtin_bit_cast(int, hi_),  \
                                               0xB1, 0xF, 0xF, true);         \
            lo_ = lo_ + __builtin_bit_cast(h2, d0_);                          \
            hi_ = hi_ + __builtin_bit_cast(h2, d1_);                          \
          }                                                                   \
          h4 hv_ = {lo_[0], lo_[1], hi_[0], hi_[1]};                          \
          *(h4*)(((ft_ == 3) ? b3_ : (BSE)) + 32 * ft_ + 8 * g_ + 4 * hw)     \
              = hv_;                                                          \
        }                                                                     \
      }                                                                       \
    }                                                                         \
  } while (0)

// B fragments for internal levels: comb row RBASE + (c & RMASK); fold t at
// k=100 (kc6, hw0 j=4), 1 at k=101; hw1 kc6 = zeros.
#define LOAD_B(BF, RBASE, RMASK, TSIB) do {                                   \
    const int cm_ = c & (RMASK);                                              \
    const int row_ = (RBASE) + cm_;                                           \
    _Pragma("unroll")                                                         \
    for (int kc_ = 0; kc_ < 6; ++kc_)                                         \
      BF[kc_] = *(const h8*)&Cs[row_][16 * kc_ + 8 * hw];                     \
    if (hw == 0) {                                                            \
      h4 lo_ = *(const h4*)&Cs[row_][96];                                     \
      h4 hi_ = {ts_fold[(TSIB) + cm_], (_Float16)1.f,                         \
                (_Float16)0.f, (_Float16)0.f};                                \
      BF[6] = __builtin_shufflevector(lo_, hi_, 0, 1, 2, 3, 4, 5, 6, 7);      \
    } else {                                                                  \
      _Pragma("unroll")                                                       \
      for (int j_ = 0; j_ < 8; ++j_) BF[6][j_] = (_Float16)0.f;               \
    }                                                                         \
  } while (0)

// Store-base pointer for a tile: even c, c<NN -> comb row WROW+(c>>1).
#define BASE_PTR(WROW, NN)                                                    \
    ((((c & 1) == 0) && (c < (NN))) ? &Cs[(WROW) + (c >> 1)][0]               \
                                    : &trash[lane * 4])

  // ---- level 8: 8 tiles; leaf comb built in packed-f16 VALU ----
  #pragma unroll 2
  for (int i = 0; i < 8; ++i) {
    const h2 tp = tsp[32 * i + c];
    const _Float16 t0 = tp[0], t1 = tp[1];
    const h8 z8 = {(_Float16)0.f, (_Float16)0.f, (_Float16)0.f, (_Float16)0.f,
                   (_Float16)0.f, (_Float16)0.f, (_Float16)0.f, (_Float16)0.f};
    h8 bf[7];
    #pragma unroll
    for (int kc = 0; kc < 7; ++kc) {
      const h8 qw8 = *(const h8*)&qwh[16 * kc + 8 * hw];
      const h8 qb8 = *(const h8*)&qbh[16 * kc + 8 * hw];
      h8 a = __builtin_elementwise_max(qw8 * t0 + qb8, z8);
      h8 b = __builtin_elementwise_max(qw8 * t1 + qb8, z8);
      bf[kc] = a + b;
    }
    if (hw == 0) {                       // fold slots k=100,101
      bf[6][4] = ts_fold[255 + 32 * i + c];
      bf[6][5] = (_Float16)1.f;
    }
    _Float16* bse = BASE_PTR(16 * i, 32);
    DO_TILE(bf, bse, 1);
  }

  // ---- level 7: 4 tiles ----
  #pragma unroll 1
  for (int i = 0; i < 4; ++i) {
    h8 bf[7];
    LOAD_B(bf, 32 * i, 31, 127 + 32 * i);
    _Float16* bse = BASE_PTR(16 * i, 32);
    DO_TILE(bf, bse, 1);
  }
  // ---- level 6: 2 tiles ----
  #pragma unroll 1
  for (int i = 0; i < 2; ++i) {
    h8 bf[7];
    LOAD_B(bf, 32 * i, 31, 63 + 32 * i);
    _Float16* bse = BASE_PTR(16 * i, 32);
    DO_TILE(bf, bse, 1);
  }
  // ---- level 5 (32 nodes) ----
  {
    h8 bf[7];
    LOAD_B(bf, 0, 31, 31);
    _Float16* bse = BASE_PTR(0, 32);
    DO_TILE(bf, bse, 1);
  }
  // ---- levels 4..1 (16,8,4,2 nodes): partial tiles ----
  #pragma unroll 1
  for (int d = 4; d >= 1; --d) {
    const int nn = 1 << d;
    h8 bf[7];
    LOAD_B(bf, 0, nn - 1, nn - 1);
    _Float16* bse = BASE_PTR(0, nn);
    DO_TILE(bf, bse, 1);
  }
  // ---- root: read comb row 0, no sibling add, store h to row 0 ----
  {
    h8 bf[7];
    LOAD_B(bf, 0, 0, 0);
    _Float16* bse = (c == 0) ? &Cs[0][0] : &trash[lane * 4];
    DO_TILE(bf, bse, 0);
  }

  // ---- projection: out[p] = root . Pw[p] + Pb[p], p<5 (wave-wide) ----
  #pragma unroll 1
  for (int p = 0; p < 5; ++p) {
    float v = (float)Cs[0][lane] * Pw[p * 100 + lane];
    if (lane < 36) v += (float)Cs[0][64 + lane] * Pw[p * 100 + 64 + lane];
    v += __shfl_xor(v, 32, 64);
    v += __shfl_xor(v, 16, 64);
    v += __shfl_xor(v, 8, 64);
    v += __shfl_xor(v, 4, 64);
    v += __shfl_xor(v, 2, 64);
    v += __shfl_xor(v, 1, 64);
    if (lane == 0) out[tree * 5 + p] = v + Pb[p];
  }
#undef DO_TILE
#undef LOAD_B
#undef BASE_PTR
}

extern "C" void kernel_launch(void* const* d_in, const int* in_sizes, int n_in,
                              void* d_out, int out_size, void* d_ws, size_t ws_size,
                              hipStream_t stream) {
  (void)n_in; (void)out_size; (void)d_ws; (void)ws_size;
  const float* times = (const float*)d_in[0];
  const float* Qw = (const float*)d_in[1];
  const float* Qb = (const float*)d_in[2];
  const float* Ww = (const float*)d_in[3];
  const float* Wb = (const float*)d_in[4];
  const float* Pw = (const float*)d_in[5];
  const float* Pb = (const float*)d_in[6];
  float* outp = (float*)d_out;
  const int B = in_sizes[0] / 1023;   // 1024 trees -> 1024 one-wave blocks
  grnn_fused<<<dim3(B), dim3(64), 0, stream>>>(times, Qw, Qb, Ww, Wb, Pw, Pb, outp);
}